// Round 10
// baseline (1860.562 us; speedup 1.0000x reference)
//
#include <hip/hip_runtime.h>
#include <hip/hip_bf16.h>
#include <cstdint>

#define B_ 16
#define N_ 2048
#define KNN_K 20
#define EPS_ 1e-5f
#define SLOPE_ 0.2f
#define IMS 4.8828125e-4f   // 1/2048

typedef __attribute__((ext_vector_type(4))) float f32x4;
typedef __attribute__((ext_vector_type(8))) short bf16x8;
typedef __attribute__((ext_vector_type(8))) _Float16 f16x8;

static __device__ __forceinline__ float lrelu(float v){ return v > 0.f ? v : SLOPE_*v; }

static __device__ __forceinline__ unsigned encf(float f){
  unsigned b = __float_as_uint(f);
  return (b & 0x80000000u) ? ~b : (b | 0x80000000u);
}
static __device__ __forceinline__ float decf(unsigned u){
  unsigned b = (u & 0x80000000u) ? (u ^ 0x80000000u) : ~u;
  return __uint_as_float(b);
}
static __device__ __forceinline__ short bfbits(float v){
  __hip_bfloat16 h = __float2bfloat16(v);
  return *reinterpret_cast<short*>(&h);
}
static __device__ __forceinline__ short h16(float v){
  _Float16 h = (_Float16)v;
  return *reinterpret_cast<short*>(&h);
}
static __device__ __forceinline__ float h2f(short s){
  _Float16 h = *reinterpret_cast<_Float16*>(&s);
  return (float)h;
}

// ---------------- convert: f -> 2 fp16 planes (h, (v-h)*2048) + xx (fp32) ----------------
template<int C, int CP>
__global__ __launch_bounds__(256) void convert_kernel(const float* __restrict__ f, int lda,
                                                      short* __restrict__ fbf, size_t plane,
                                                      float* __restrict__ xx){
  int wid  = (blockIdx.x * 256 + threadIdx.x) >> 6;   // one wave per row
  int lane = threadIdx.x & 63;
  if (wid >= B_*N_) return;
  const float* p = f + (size_t)wid*lda;
  float s = 0.f;
  for (int c = lane; c < CP; c += 64){
    float v = (c < C) ? p[c] : 0.f;
    short h = h16(v);
    short m = h16((v - h2f(h)) * 2048.f);
    size_t o = (size_t)wid*CP + c;
    fbf[o] = h;
    fbf[plane + o] = m;
    s += v*v;
  }
  #pragma unroll
  for (int off=32; off; off>>=1) s += __shfl_down(s, off);
  if (lane==0) xx[wid] = s;
}

// ---------------- fused MFMA distance (fp16 2-plane) + max-first wave-coop top-20, m-split ----------------
// grid: B * 32 n-tiles * 2 m-halves. block: 256 threads (4 waves), 64 n-rows, 16 m-tiles.
// Stored value = 2*dot - xm (row-uniform -xn dropped: monotone per-row shift, same across halves).
// Selection: candidates in regs c[16]; per round pop the row MAX (DPP quad-reduce, id-asc ties),
// insert into distributed sorted-20 (4 lanes x 5 ranks), then thr=min4(sv[4]) refilters c.
template<int CP>
__global__ __launch_bounds__(256) void knn_mfma(const short* __restrict__ fbf, size_t plane,
                                                const float* __restrict__ xx,
                                                float* __restrict__ pval, int* __restrict__ pidx){
  constexpr int SP = CP + 8;          // shorts per LDS row
  constexpr int CH = CP/8;
  constexpr int KC = CP/32;
  constexpr int PFH = CP/32;          // 16B chunks per thread per plane
  __shared__ __align__(16) short fmb[2*64*SP];
  __shared__ float dtile[64*65];
  __shared__ float xm_s[64];

  int b   = blockIdx.x >> 6;
  int rem = blockIdx.x & 63;
  int n0  = (rem >> 1) << 6;
  int mh  = rem & 1;
  int mbase = mh << 10;
  int tid = threadIdx.x;
  int w    = tid >> 6;
  int lane = tid & 63;
  int fr = lane & 15, hi = lane >> 4;
  int r_loc = lane >> 2, csub = lane & 3;
  int myrow = w*16 + r_loc;
  size_t browoff = (size_t)b * N_;

  // fn A-fragments -- m-tile invariant, registers
  f16x8 aH[KC], aM[KC];
  {
    size_t arow = (browoff + n0 + w*16 + fr) * (size_t)CP;
    #pragma unroll
    for (int kc=0; kc<KC; ++kc){
      aH[kc] = *(const f16x8*)&fbf[arow + kc*32 + hi*8];
      aM[kc] = *(const f16x8*)&fbf[plane + arow + kc*32 + hi*8];
    }
  }

  float sv[5]; int si[5];
  #pragma unroll
  for (int j=0;j<5;++j){ sv[j] = -1e30f; si[j] = 0x7FFFFFFF; }

  // hoisted staging: per-thread chunk (r, cq) is tile-invariant; CH is pow2
  int ldso[PFH];
  const short* gH[PFH];           // H srcs; M src = gH + plane
  #pragma unroll
  for (int j=0;j<PFH;++j){
    int i = tid + j*256;
    int r = i/CH, cq = i - r*CH;
    ldso[j] = r*SP + cq*8;
    gH[j] = fbf + (browoff + mbase + r)*(size_t)CP + cq*8;
  }
  const float* xmp = xx + browoff + mbase + (tid & 63);
  float xmreg = 0.f;

  f16x8 pf[PFH], pm[PFH];         // both planes prefetched to regs
  auto PFLOAD = [&](){
    #pragma unroll
    for (int j=0;j<PFH;++j){
      pf[j] = *(const f16x8*)gH[j];
      pm[j] = *(const f16x8*)(gH[j] + plane);
    }
    if (tid < 64) xmreg = *xmp;
  };
  auto WRITEPF = [&](){
    #pragma unroll
    for (int j=0;j<PFH;++j){
      *(f16x8*)&fmb[ldso[j]] = pf[j];
      *(f16x8*)&fmb[64*SP + ldso[j]] = pm[j];
      gH[j] += 64*CP;
    }
    if (tid < 64) xm_s[tid] = xmreg;
    xmp += 64;
  };

  PFLOAD();
  WRITEPF();
  __syncthreads();

  for (int mt = 0; mt < 16; ++mt){
    int m0 = mbase + (mt << 6);
    if (mt + 1 < 16) PFLOAD();   // next tile loads in flight during MFMA+selection

    // 3 terms: accH = h.h ; accM = m'.h + h.m'  -> dot = accH + accM/2048
    f32x4 accH[4], accM[4];
    #pragma unroll
    for (int ct=0; ct<4; ++ct){ accH[ct] = (f32x4){0.f,0.f,0.f,0.f}; accM[ct] = accH[ct]; }
    const short* BH = fmb;
    const short* BM = fmb + 64*SP;
    #pragma unroll
    for (int kc = 0; kc < KC; ++kc){
      #pragma unroll
      for (int ct=0; ct<4; ++ct){
        int boff = (ct*16 + fr)*SP + kc*32 + hi*8;
        f16x8 bh = *(const f16x8*)&BH[boff];
        f16x8 bm = *(const f16x8*)&BM[boff];
        accH[ct] = __builtin_amdgcn_mfma_f32_16x16x32_f16(aH[kc], bh, accH[ct], 0,0,0);
        accM[ct] = __builtin_amdgcn_mfma_f32_16x16x32_f16(aM[kc], bh, accM[ct], 0,0,0);
        accM[ct] = __builtin_amdgcn_mfma_f32_16x16x32_f16(aH[kc], bm, accM[ct], 0,0,0);
      }
    }
    // dtile: D row=(lane>>4)*4+reg, col=lane&15 per 16x16 tile (own-wave rows only)
    #pragma unroll
    for (int reg=0; reg<4; ++reg){
      int nl = w*16 + hi*4 + reg;
      #pragma unroll
      for (int ct=0; ct<4; ++ct)
        dtile[nl*65 + ct*16 + fr] = 2.f*(accH[ct][reg] + IMS*accM[ct][reg]) - xm_s[ct*16 + fr];
    }
    if (mt + 1 < 16) __syncthreads();   // all waves' fmb reads done (WAR for next WRITEPF)

    // ---- max-first selection (c[] in regs, all-DPP cross-lane) ----
    int base = myrow*65 + csub*16;
    float c[16];
    #pragma unroll
    for (int jj=0;jj<16;++jj) c[jj] = dtile[base + jj];
    float t0 = fminf(sv[4], __shfl_xor(sv[4],1));
    float thr = fminf(t0, __shfl_xor(t0,2));        // row's rank-19 value
    #pragma unroll
    for (int jj=0;jj<16;++jj) c[jj] = (c[jj] > thr) ? c[jj] : -3e38f;

    while (true){
      // lane argmax (strict > gives lower j on ties -> lower id)
      float lv = c[0]; int lj = 0;
      #pragma unroll
      for (int jj=1;jj<16;++jj){ bool bt = c[jj] > lv; lv = bt ? c[jj] : lv; lj = bt ? jj : lj; }
      int lid = m0 + (csub<<4) + lj;
      // row argmax across 4 lanes (value desc, id asc)
      float rv = lv; int rid = lid;
      { float ov = __shfl_xor(rv,1); int oid = __shfl_xor(rid,1);
        bool tk = (ov > rv) || (ov == rv && oid < rid); rv = tk?ov:rv; rid = tk?oid:rid; }
      { float ov = __shfl_xor(rv,2); int oid = __shfl_xor(rid,2);
        bool tk = (ov > rv) || (ov == rv && oid < rid); rv = tk?ov:rv; rid = tk?oid:rid; }
      if (!__ballot(rv > -2.9e38f)) break;
      // insert (rv,rid) into distributed sorted-20; pos<=19 guaranteed when row live
      int cnt = 0;
      #pragma unroll
      for (int j=0;j<5;++j) cnt += (sv[j] >= rv) ? 1 : 0;
      cnt += __shfl_xor(cnt,1);
      cnt += __shfl_xor(cnt,2);
      int pos = (rv > -2.9e38f) ? cnt : 20;
      float pvv = __shfl_up(sv[4],1);
      int   pii = __shfl_up(si[4],1);
      #pragma unroll
      for (int j=0;j<5;++j){
        int g = csub*5 + j;
        float ns = (g < pos) ? sv[j] : ((g == pos) ? rv : pvv);
        int   ni = (g < pos) ? si[j] : ((g == pos) ? rid : pii);
        pvv = sv[j]; pii = si[j];
        sv[j] = ns; si[j] = ni;
      }
      // tighten threshold, clear popped candidate + refilter
      float u0 = fminf(sv[4], __shfl_xor(sv[4],1));
      thr = fminf(u0, __shfl_xor(u0,2));
      bool own = (lid == rid);
      #pragma unroll
      for (int jj=0;jj<16;++jj){
        bool kill = (own && jj==lj) || !(c[jj] > thr);
        c[jj] = kill ? -3e38f : c[jj];
      }
    }

    if (mt + 1 < 16){
      WRITEPF();          // pure reg->LDS (loads landed during MFMA+selection)
      __syncthreads();    // fmb(t+1)+xm_s ready
    }
  }

  // emit partial sorted list: lane csub holds ranks csub*5..csub*5+4
  size_t orow = browoff + n0 + myrow;
  float* pvo = pval + (orow*2 + mh)*KNN_K + csub*5;
  int*   pio = pidx + (orow*2 + mh)*KNN_K + csub*5;
  #pragma unroll
  for (int j=0;j<5;++j){ pvo[j] = sv[j]; pio[j] = si[j]; }
}

// ---------------- merge two sorted-20 partial lists per row ----------------
__global__ __launch_bounds__(256) void knn_merge(const float* __restrict__ pval,
                                                 const int* __restrict__ pidx,
                                                 int* __restrict__ idxout){
  int r = blockIdx.x*256 + threadIdx.x;
  if (r >= B_*N_) return;
  const float* va = pval + (size_t)r*2*KNN_K;
  const float* vb = va + KNN_K;
  const int*   ia = pidx + (size_t)r*2*KNN_K;
  const int*   ib = ia + KNN_K;
  int i=0, j=0;
  #pragma unroll
  for (int t=0;t<KNN_K;++t){
    float a = va[i], bq = vb[j];
    bool ta = (a >= bq);   // tie -> half 0 (lower ids)
    idxout[(size_t)r*KNN_K + t] = ta ? ia[i] : ib[j];
    i += ta ? 1 : 0; j += ta ? 0 : 1;
  }
}

// ---------------- P/Q GEMM via fp16 2-plane MFMA: Out[M,O] = f * Wsrc[O x Cin]^T ----------------
template<int CP>
__global__ __launch_bounds__(256) void gemm_pq(const short* __restrict__ fbf, size_t plane,
                                               const float* __restrict__ Wsrc, int wstride, int Cin,
                                               float* __restrict__ Out, int O){
  constexpr int BK = (CP < 64) ? CP : 64;
  constexpr int SP = BK + 8;
  __shared__ short Ah[128*SP];
  __shared__ short Am[128*SP];
  __shared__ short Wh[64*SP];
  __shared__ short Wm[64*SP];
  int obl = O >> 6;
  int bo = ((int)blockIdx.x % obl) << 6;
  int bm = ((int)blockIdx.x / obl) << 7;
  int tid = threadIdx.x;
  int w = tid >> 6, lane = tid & 63;
  int fr = lane & 15, hi = lane >> 4;
  f32x4 accH[2][4], accM[2][4];
  #pragma unroll
  for (int g=0; g<2; ++g)
    #pragma unroll
    for (int ct=0; ct<4; ++ct){ accH[g][ct] = (f32x4){0.f,0.f,0.f,0.f}; accM[g][ct] = accH[g][ct]; }

  for (int k0=0; k0<CP; k0+=BK){
    __syncthreads();
    for (int i=tid; i < 128*(BK/8); i += 256){
      int r = i/(BK/8), cq = i%(BK/8);
      size_t src = ((size_t)bm + r)*CP + k0 + cq*8;
      *(f16x8*)&Ah[r*SP + cq*8] = *(const f16x8*)&fbf[src];
      *(f16x8*)&Am[r*SP + cq*8] = *(const f16x8*)&fbf[plane + src];
    }
    for (int i=tid; i < 64*(BK/8); i += 256){
      int r = i/(BK/8), cq = i%(BK/8);
      f16x8 vh, vm;
      #pragma unroll
      for (int e=0;e<8;++e){
        int c = k0 + cq*8 + e;
        float v = (c < Cin) ? Wsrc[(size_t)(bo + r)*wstride + c] : 0.f;
        _Float16 h = (_Float16)v;
        vh[e] = h;
        vm[e] = (_Float16)((v - (float)h) * 2048.f);
      }
      *(f16x8*)&Wh[r*SP + cq*8] = vh;
      *(f16x8*)&Wm[r*SP + cq*8] = vm;
    }
    __syncthreads();
    #pragma unroll
    for (int kc=0; kc<BK/32; ++kc){
      f16x8 a0h = *(const f16x8*)&Ah[(w*32 +      fr)*SP + kc*32 + hi*8];
      f16x8 a0m = *(const f16x8*)&Am[(w*32 +      fr)*SP + kc*32 + hi*8];
      f16x8 a1h = *(const f16x8*)&Ah[(w*32 + 16 + fr)*SP + kc*32 + hi*8];
      f16x8 a1m = *(const f16x8*)&Am[(w*32 + 16 + fr)*SP + kc*32 + hi*8];
      #pragma unroll
      for (int ct=0; ct<4; ++ct){
        f16x8 bh = *(const f16x8*)&Wh[(ct*16 + fr)*SP + kc*32 + hi*8];
        f16x8 bm = *(const f16x8*)&Wm[(ct*16 + fr)*SP + kc*32 + hi*8];
        accH[0][ct] = __builtin_amdgcn_mfma_f32_16x16x32_f16(a0h, bh, accH[0][ct], 0,0,0);
        accM[0][ct] = __builtin_amdgcn_mfma_f32_16x16x32_f16(a0m, bh, accM[0][ct], 0,0,0);
        accM[0][ct] = __builtin_amdgcn_mfma_f32_16x16x32_f16(a0h, bm, accM[0][ct], 0,0,0);
        accH[1][ct] = __builtin_amdgcn_mfma_f32_16x16x32_f16(a1h, bh, accH[1][ct], 0,0,0);
        accM[1][ct] = __builtin_amdgcn_mfma_f32_16x16x32_f16(a1m, bh, accM[1][ct], 0,0,0);
        accM[1][ct] = __builtin_amdgcn_mfma_f32_16x16x32_f16(a1h, bm, accM[1][ct], 0,0,0);
      }
    }
  }
  #pragma unroll
  for (int g=0; g<2; ++g)
    #pragma unroll
    for (int ct=0; ct<4; ++ct)
      #pragma unroll
      for (int reg=0; reg<4; ++reg){
        int row = bm + w*32 + g*16 + hi*4 + reg;
        Out[(size_t)row*O + bo + ct*16 + fr] = accH[g][ct][reg] + IMS*accM[g][ct][reg];
      }
}

// ---------------- conv5 MFMA GEMM: C[M,512] = A[M,512]fp32 x W[512,512]fp32^T (bf16 staged) ----------------
__global__ __launch_bounds__(256) void gemm_bf16(const float* __restrict__ A,
                                                 const float* __restrict__ Wt,
                                                 float* __restrict__ C){
  __shared__ short As[128*72];
  __shared__ short Bs[64*72];
  int bm = (int)(blockIdx.x >> 3) << 7;
  int bo = (int)(blockIdx.x & 7) << 6;
  int tid = threadIdx.x;
  int w = tid >> 6, lane = tid & 63;
  int fr = lane & 15, hi = lane >> 4;
  f32x4 acc[2][4];
  #pragma unroll
  for (int g=0; g<2; ++g)
    #pragma unroll
    for (int ct=0; ct<4; ++ct) acc[g][ct] = (f32x4){0.f,0.f,0.f,0.f};

  for (int k0=0; k0<512; k0+=64){
    __syncthreads();
    #pragma unroll 2
    for (int i = tid; i < 1024; i += 256){
      int r = i >> 3, cq = i & 7;
      const float* src = &A[(size_t)(bm + r)*512 + k0 + cq*8];
      bf16x8 v;
      #pragma unroll
      for (int e=0;e<8;++e) v[e] = bfbits(src[e]);
      *(bf16x8*)&As[r*72 + cq*8] = v;
    }
    #pragma unroll 2
    for (int i = tid; i < 512; i += 256){
      int r = i >> 3, cq = i & 7;
      const float* src = &Wt[(size_t)(bo + r)*512 + k0 + cq*8];
      bf16x8 v;
      #pragma unroll
      for (int e=0;e<8;++e) v[e] = bfbits(src[e]);
      *(bf16x8*)&Bs[r*72 + cq*8] = v;
    }
    __syncthreads();
    #pragma unroll
    for (int kc=0; kc<2; ++kc){
      bf16x8 a0 = *(const bf16x8*)&As[(w*32 +      fr)*72 + kc*32 + hi*8];
      bf16x8 a1 = *(const bf16x8*)&As[(w*32 + 16 + fr)*72 + kc*32 + hi*8];
      #pragma unroll
      for (int ct=0; ct<4; ++ct){
        bf16x8 bb = *(const bf16x8*)&Bs[(ct*16 + fr)*72 + kc*32 + hi*8];
        acc[0][ct] = __builtin_amdgcn_mfma_f32_16x16x32_bf16(a0, bb, acc[0][ct], 0,0,0);
        acc[1][ct] = __builtin_amdgcn_mfma_f32_16x16x32_bf16(a1, bb, acc[1][ct], 0,0,0);
      }
    }
  }
  #pragma unroll
  for (int g=0; g<2; ++g)
    #pragma unroll
    for (int ct=0; ct<4; ++ct)
      #pragma unroll
      for (int reg=0; reg<4; ++reg){
        int row = bm + w*32 + g*16 + hi*4 + reg;
        C[(size_t)row*512 + bo + ct*16 + fr] = acc[g][ct][reg];
      }
}

// ---------------- wq = wB - wA ----------------
__global__ void wq_kernel(const float* __restrict__ w, float* __restrict__ wq, int Cin, int O){
  int i = blockIdx.x*blockDim.x + threadIdx.x;
  if (i >= O*Cin) return;
  int o = i / Cin, c = i - o*Cin;
  wq[i] = w[(size_t)o*2*Cin + Cin + c] - w[(size_t)o*2*Cin + c];
}

__global__ void zero_f_kernel(float* p, int n){
  int i = blockIdx.x*blockDim.x + threadIdx.x;
  if (i < n) p[i] = 0.f;
}
__global__ void zero_u_kernel(unsigned* p, int n){
  int i = blockIdx.x*blockDim.x + threadIdx.x;
  if (i < n) p[i] = 0u;
}

// ---------------- edge aggregation: gather P, stats + selected extreme ----------------
__global__ __launch_bounds__(256) void edge_agg(const float* __restrict__ P, const float* __restrict__ Q,
      const int* __restrict__ idx, const float* __restrict__ gamma,
      float* __restrict__ S, float* __restrict__ sums, float* __restrict__ sumsq, int O){
  const int ROWS = 64;
  int rpi = 256 / O;
  int iters = ROWS / rpi;
  int row0 = blockIdx.x * ROWS;
  int tid = threadIdx.x;
  int o  = tid % O;
  int rl = tid / O;
  int b  = row0 / N_;
  __shared__ int sidx[4][KNN_K];
  __shared__ float s1[256], s2[256];
  float g = gamma[o];
  float csum=0.f, csumsq=0.f;
  for (int it=0; it<iters; ++it){
    __syncthreads();
    if (tid < KNN_K*rpi) sidx[tid/KNN_K][tid%KNN_K] = idx[(size_t)(row0 + it*rpi)*KNN_K + tid];
    __syncthreads();
    int row = row0 + it*rpi + rl;
    float q = Q[(size_t)row*O + o];
    float mx=-1e30f, mn=1e30f, s=0.f, ss=0.f;
    #pragma unroll
    for (int k=0;k<KNN_K;++k){
      int m = sidx[rl][k];
      float p = P[((size_t)b*N_ + m)*O + o];
      mx = fmaxf(mx,p); mn = fminf(mn,p);
      float y = p + q; s += y; ss += y*y;
    }
    csum += s; csumsq += ss;
    S[(size_t)row*O + o] = (g >= 0.f ? mx : mn) + q;
  }
  s1[tid]=0.f; s2[tid]=0.f;
  __syncthreads();
  atomicAdd(&s1[o], csum); atomicAdd(&s2[o], csumsq);
  __syncthreads();
  if (tid < O){ atomicAdd(&sums[tid], s1[tid]); atomicAdd(&sumsq[tid], s2[tid]); }
}

// ---------------- BN finalize ----------------
__global__ void bn_finalize(const float* __restrict__ sums, const float* __restrict__ sumsq,
                            const float* __restrict__ gamma, const float* __restrict__ beta,
                            float invM, float* __restrict__ scale, float* __restrict__ shift, int O){
  int o = blockIdx.x*blockDim.x + threadIdx.x;
  if (o >= O) return;
  float mu = sums[o]*invM;
  float var = sumsq[o]*invM - mu*mu;
  float rs = rsqrtf(var + EPS_);
  float sc = gamma[o]*rs;
  scale[o] = sc; shift[o] = beta[o] - mu*sc;
}

// ---------------- apply affine+lrelu, write into cat ----------------
__global__ void apply_write(const float* __restrict__ S, const float* __restrict__ scale,
                            const float* __restrict__ shift, float* __restrict__ cat, int off, int O){
  int i = blockIdx.x*blockDim.x + threadIdx.x;
  if (i >= B_*N_*O) return;
  int row = i / O, o = i - row*O;
  float v = S[i]*scale[o] + shift[o];
  cat[(size_t)row*512 + off + o] = lrelu(v);
}

// ---------------- conv5 stats ----------------
__global__ __launch_bounds__(256) void conv5_stats(const float* __restrict__ Y, const float* __restrict__ g5,
      float* __restrict__ sums, float* __restrict__ sumsq, unsigned* __restrict__ maxenc){
  int bb = blockIdx.x / 16;
  int n0 = (blockIdx.x % 16) * 128;
  int tid = threadIdx.x;
  float s0=0.f, s1=0.f, q0=0.f, q1=0.f, m0=-1e30f, m1=-1e30f;
  float ga = g5[tid], gb = g5[tid+256];
  for (int n=0;n<128;++n){
    size_t base = ((size_t)bb*N_ + n0 + n)*512;
    float ya = Y[base + tid];
    float yb = Y[base + tid + 256];
    s0 += ya; q0 += ya*ya;
    s1 += yb; q1 += yb*yb;
    m0 = fmaxf(m0, ga>=0.f ? ya : -ya);
    m1 = fmaxf(m1, gb>=0.f ? yb : -yb);
  }
  atomicAdd(&sums[tid],      s0); atomicAdd(&sumsq[tid],      q0);
  atomicAdd(&sums[tid+256],  s1); atomicAdd(&sumsq[tid+256],  q1);
  atomicMax(&maxenc[bb*512 + tid],       encf(m0));
  atomicMax(&maxenc[bb*512 + tid + 256], encf(m1));
}

// ---------------- pool ----------------
__global__ void pool_kernel(const unsigned* __restrict__ maxenc, const float* __restrict__ scale,
                            const float* __restrict__ shift, const float* __restrict__ g5,
                            float* __restrict__ pooled){
  int i = blockIdx.x*blockDim.x + threadIdx.x;
  if (i >= B_*512) return;
  int o = i & 511;
  float t = decf(maxenc[i]);
  float y = g5[o] >= 0.f ? t : -t;
  pooled[i] = lrelu(y*scale[o] + shift[o]);
}

// ---------------- final projection ----------------
__global__ void final_mm(const float* __restrict__ pooled, const float* __restrict__ we,
                         float* __restrict__ out){
  int i = blockIdx.x*blockDim.x + threadIdx.x;
  if (i >= B_*128) return;
  int b = i >> 7, j = i & 127;
  const float4* pp = (const float4*)(pooled + (size_t)b*512);
  const float4* wp = (const float4*)(we + (size_t)j*512);
  float s = 0.f;
  for (int c=0;c<128;++c){
    float4 a = pp[c], w = wp[c];
    s += a.x*w.x + a.y*w.y + a.z*w.z + a.w*w.w;
  }
  out[i] = s;
}

// ---------------- driver ----------------
struct Ws {
  float* cat; float* P; float* Q; float* S; int* idx; float* xx;
  float* sums; float* sumsq; float* scale; float* shift;
  float* wq; unsigned* maxenc; float* pooled; short* fbf;
  float* pval; int* pidx;
};

template<int C, int CP>
static void run_layer(const Ws& W, const float* f, int lda, int O,
                      const float* w, const float* g, const float* bt,
                      int off_out, hipStream_t stream){
  const int M = B_*N_;
  size_t plane = (size_t)M*CP;
  convert_kernel<C, CP><<<M/4, 256, 0, stream>>>(f, lda, W.fbf, plane, W.xx);
  knn_mfma<CP><<<B_*(N_/64)*2, 256, 0, stream>>>(W.fbf, plane, W.xx, W.pval, W.pidx);
  knn_merge<<<(M+255)/256, 256, 0, stream>>>(W.pval, W.pidx, W.idx);
  int nwq = O*C;
  wq_kernel<<<(nwq+255)/256, 256, 0, stream>>>(w, W.wq, C, O);
  int grid = (M/128)*(O/64);
  gemm_pq<CP><<<grid, 256, 0, stream>>>(W.fbf, plane, w,    2*C, C, W.P, O);
  gemm_pq<CP><<<grid, 256, 0, stream>>>(W.fbf, plane, W.wq, C,   C, W.Q, O);
  zero_f_kernel<<<4, 256, 0, stream>>>(W.sums, 1024);
  edge_agg<<<M/64, 256, 0, stream>>>(W.P, W.Q, W.idx, g, W.S, W.sums, W.sumsq, O);
  bn_finalize<<<(O+255)/256, 256, 0, stream>>>(W.sums, W.sumsq, g, bt,
                                               1.f/((float)M*KNN_K), W.scale, W.shift, O);
  apply_write<<<(M*O+255)/256, 256, 0, stream>>>(W.S, W.scale, W.shift, W.cat, off_out, O);
}

extern "C" void kernel_launch(void* const* d_in, const int* in_sizes, int n_in,
                              void* d_out, int out_size, void* d_ws, size_t ws_size,
                              hipStream_t stream) {
  const float* x  = (const float*)d_in[0];
  const float* w1 = (const float*)d_in[1];
  const float* g1 = (const float*)d_in[2];
  const float* b1 = (const float*)d_in[3];
  const float* w2 = (const float*)d_in[4];
  const float* g2 = (const float*)d_in[5];
  const float* b2 = (const float*)d_in[6];
  const float* w3 = (const float*)d_in[7];
  const float* g3 = (const float*)d_in[8];
  const float* b3 = (const float*)d_in[9];
  const float* w4 = (const float*)d_in[10];
  const float* g4 = (const float*)d_in[11];
  const float* b4 = (const float*)d_in[12];
  const float* w5 = (const float*)d_in[13];
  const float* g5 = (const float*)d_in[14];
  const float* b5 = (const float*)d_in[15];
  const float* we = (const float*)d_in[16];

  char* ws = (char*)d_ws;
  Ws W;
  size_t off = 0;
  W.cat   = (float*)(ws + off); off += (size_t)16*2048*512*4;
  W.P     = (float*)(ws + off); off += (size_t)16*2048*256*4;
  W.Q     = (float*)(ws + off); off += (size_t)16*2048*256*4;
  W.S     = (float*)(ws + off); off += (size_t)16*2048*256*4;
  W.idx   = (int*)  (ws + off); off += (size_t)16*2048*20*4;
  W.xx    = (float*)(ws + off); off += (size_t)16*2048*4;
  W.sums  = (float*)(ws + off); off += 512*4;
  W.sumsq = (float*)(ws + off); off += 512*4;
  W.scale = (float*)(ws + off); off += 512*4;
  W.shift = (float*)(ws + off); off += 512*4;
  W.wq    = (float*)(ws + off); off += (size_t)256*128*4;
  W.maxenc= (unsigned*)(ws + off); off += (size_t)16*512*4;
  W.pooled= (float*)(ws + off); off += (size_t)16*512*4;
  W.fbf   = (short*)W.S;            // fbf live [convert, gemm_pq]; S live [edge_agg, apply_write]
  W.pval  = W.Q;                    // partials live [knn, merge]; Q live [gemm_pq, edge_agg]
  W.pidx  = (int*)(W.Q + (size_t)2*16*2048*KNN_K);

  const int M = B_*N_;

  run_layer<3,   32>(W, x,           3,   64,  w1, g1, b1, 0,   stream);
  run_layer<64,  64>(W, W.cat,       512, 64,  w2, g2, b2, 64,  stream);
  run_layer<64,  64>(W, W.cat + 64,  512, 128, w3, g3, b3, 128, stream);
  run_layer<128,128>(W, W.cat + 128, 512, 256, w4, g4, b4, 256, stream);

  // conv5 via bf16 MFMA; y5 reuses P+Q region
  float* y5 = W.P;
  gemm_bf16<<<(M/128)*8, 256, 0, stream>>>(W.cat, w5, y5);
  zero_f_kernel<<<4, 256, 0, stream>>>(W.sums, 1024);
  zero_u_kernel<<<32, 256, 0, stream>>>(W.maxenc, 16*512);
  conv5_stats<<<B_*16, 256, 0, stream>>>(y5, g5, W.sums, W.sumsq, W.maxenc);
  bn_finalize<<<2, 256, 0, stream>>>(W.sums, W.sumsq, g5, b5, 1.f/(float)M, W.scale, W.shift, 512);
  pool_kernel<<<(16*512+255)/256, 256, 0, stream>>>(W.maxenc, W.scale, W.shift, g5, W.pooled);
  final_mm<<<(16*128+255)/256, 256, 0, stream>>>(W.pooled, we, (float*)d_out);
}

// Round 11
// 1303.976 us; speedup vs baseline: 1.4268x; 1.4268x over previous
//
#include <hip/hip_runtime.h>
#include <hip/hip_bf16.h>
#include <cstdint>

#define B_ 16
#define N_ 2048
#define KNN_K 20
#define EPS_ 1e-5f
#define SLOPE_ 0.2f
#define IMS 4.8828125e-4f   // 1/2048

typedef __attribute__((ext_vector_type(4))) float f32x4;
typedef __attribute__((ext_vector_type(8))) short bf16x8;
typedef __attribute__((ext_vector_type(8))) _Float16 f16x8;

static __device__ __forceinline__ float lrelu(float v){ return v > 0.f ? v : SLOPE_*v; }

static __device__ __forceinline__ unsigned encf(float f){
  unsigned b = __float_as_uint(f);
  return (b & 0x80000000u) ? ~b : (b | 0x80000000u);
}
static __device__ __forceinline__ float decf(unsigned u){
  unsigned b = (u & 0x80000000u) ? (u ^ 0x80000000u) : ~u;
  return __uint_as_float(b);
}
static __device__ __forceinline__ short bfbits(float v){
  __hip_bfloat16 h = __float2bfloat16(v);
  return *reinterpret_cast<short*>(&h);
}
static __device__ __forceinline__ short h16(float v){
  _Float16 h = (_Float16)v;
  return *reinterpret_cast<short*>(&h);
}
static __device__ __forceinline__ float h2f(short s){
  _Float16 h = *reinterpret_cast<_Float16*>(&s);
  return (float)h;
}

// ---------------- convert: f -> 2 fp16 planes (h, (v-h)*2048) + xx (fp32) ----------------
template<int C, int CP>
__global__ __launch_bounds__(256) void convert_kernel(const float* __restrict__ f, int lda,
                                                      short* __restrict__ fbf, size_t plane,
                                                      float* __restrict__ xx){
  int wid  = (blockIdx.x * 256 + threadIdx.x) >> 6;   // one wave per row
  int lane = threadIdx.x & 63;
  if (wid >= B_*N_) return;
  const float* p = f + (size_t)wid*lda;
  float s = 0.f;
  for (int c = lane; c < CP; c += 64){
    float v = (c < C) ? p[c] : 0.f;
    short h = h16(v);
    short m = h16((v - h2f(h)) * 2048.f);
    size_t o = (size_t)wid*CP + c;
    fbf[o] = h;
    fbf[plane + o] = m;
    s += v*v;
  }
  #pragma unroll
  for (int off=32; off; off>>=1) s += __shfl_down(s, off);
  if (lane==0) xx[wid] = s;
}

// ---------------- barrier-free fused MFMA distance + wave-coop top-20 ----------------
// grid: B * 128 n-blocks(16 rows) * 2 m-halves = 4096 blocks x 64 threads (1 wave).
// B-fragments read straight from global (per-batch planes are L2-resident).
// dtile is wave-private LDS (same-wave RAW; no __syncthreads anywhere).
// Stored value = 2*dot - xm (row-uniform -xn dropped: monotone per-row shift).
// Selection: r8-proven ballot scheme, 4 lanes/row x 5 ranks distributed sorted list.
template<int CP>
__global__ __launch_bounds__(64) void knn_nb(const short* __restrict__ fbf, size_t plane,
                                             const float* __restrict__ xx,
                                             float* __restrict__ pval, int* __restrict__ pidx){
  constexpr int KC = CP/32;
  __shared__ float dtile[16*65];

  int b    = blockIdx.x >> 8;          // 256 blocks per batch
  int rem  = blockIdx.x & 255;
  int nblk = rem >> 1;                 // 0..127
  int mh   = rem & 1;
  int mbase = mh << 10;
  int lane = threadIdx.x;
  int fr = lane & 15, hi = lane >> 4;
  int r_loc = lane >> 2, csub = lane & 3;
  int gb = lane & 60;
  int n0 = nblk << 4;
  size_t browoff = (size_t)b * N_;

  // A-fragments for the 16 rows (row = n0+fr), m-invariant
  f16x8 aH[KC], aM[KC];
  {
    size_t arow = (browoff + n0 + fr) * (size_t)CP;
    #pragma unroll
    for (int kc=0; kc<KC; ++kc){
      aH[kc] = *(const f16x8*)&fbf[arow + kc*32 + hi*8];
      aM[kc] = *(const f16x8*)&fbf[plane + arow + kc*32 + hi*8];
    }
  }

  float sv[5]; int si[5];
  #pragma unroll
  for (int j=0;j<5;++j){ sv[j] = -1e30f; si[j] = 0x7FFFFFFF; }

  for (int mt = 0; mt < 16; ++mt){
    int m0 = mbase + (mt << 6);

    // 4 column sub-tiles: B-frags from global, 3-term fp16-split MFMA
    #pragma unroll
    for (int ct=0; ct<4; ++ct){
      const short* bb = fbf + (browoff + m0 + ct*16 + fr)*(size_t)CP + hi*8;
      f16x8 bh[KC], bm[KC];
      #pragma unroll
      for (int kc=0; kc<KC; ++kc){
        bh[kc] = *(const f16x8*)(bb + kc*32);
        bm[kc] = *(const f16x8*)(bb + plane + kc*32);
      }
      f32x4 accH = (f32x4){0.f,0.f,0.f,0.f};
      f32x4 accM = accH;
      #pragma unroll
      for (int kc=0; kc<KC; ++kc){
        accH = __builtin_amdgcn_mfma_f32_16x16x32_f16(aH[kc], bh[kc], accH, 0,0,0);
        accM = __builtin_amdgcn_mfma_f32_16x16x32_f16(aM[kc], bh[kc], accM, 0,0,0);
        accM = __builtin_amdgcn_mfma_f32_16x16x32_f16(aH[kc], bm[kc], accM, 0,0,0);
      }
      float xm = xx[browoff + m0 + ct*16 + fr];
      // D layout: row=(lane>>4)*4+reg, col=lane&15 -> rows hi*4+reg, col ct*16+fr
      #pragma unroll
      for (int reg=0; reg<4; ++reg)
        dtile[(hi*4+reg)*65 + ct*16 + fr] = 2.f*(accH[reg] + IMS*accM[reg]) - xm;
    }

    // ---- wave-cooperative selection (r8-proven) ----
    int base = r_loc*65 + csub*16;
    float thr = __shfl(sv[4], lane | 3);   // row's current rank-19 value
    unsigned qm = 0u;
    #pragma unroll
    for (int jj=0; jj<16; ++jj){
      float v = dtile[base + jj];
      qm |= (v > thr) ? (1u << jj) : 0u;
    }
    unsigned long long bal = __ballot(qm != 0u);
    while (bal){
      unsigned nib = (unsigned)((bal >> gb) & 0xFull);
      int leader = nib ? (gb + (int)__builtin_ctz(nib)) : 64;
      int bbit = (int)__builtin_ctz(qm | 0x10000u);
      float mv = dtile[base + (bbit & 15)];
      int mid = m0 + (csub << 4) + bbit;
      float cv = __shfl(mv, leader);
      int   cid = __shfl(mid, leader);
      qm = (lane == leader) ? (qm & (qm - 1u)) : qm;
      int cnt = 0;
      #pragma unroll
      for (int j=0;j<5;++j) cnt += (sv[j] >= cv) ? 1 : 0;
      cnt += __shfl_xor(cnt, 1);
      cnt += __shfl_xor(cnt, 2);
      int pos = nib ? cnt : 20;
      float pv = __shfl_up(sv[4], 1);
      int   pi = __shfl_up(si[4], 1);
      #pragma unroll
      for (int j=0;j<5;++j){
        int g = csub*5 + j;
        float ns = (g < pos) ? sv[j] : ((g == pos) ? cv : pv);
        int   ni = (g < pos) ? si[j] : ((g == pos) ? cid : pi);
        pv = sv[j]; pi = si[j];
        sv[j] = ns; si[j] = ni;
      }
      bal = __ballot(qm != 0u);
    }
  }

  // emit partial sorted list: lane csub holds ranks csub*5..csub*5+4
  size_t orow = browoff + n0 + r_loc;
  float* pvo = pval + (orow*2 + mh)*KNN_K + csub*5;
  int*   pio = pidx + (orow*2 + mh)*KNN_K + csub*5;
  #pragma unroll
  for (int j=0;j<5;++j){ pvo[j] = sv[j]; pio[j] = si[j]; }
}

// ---------------- merge two sorted-20 partial lists per row ----------------
__global__ __launch_bounds__(256) void knn_merge(const float* __restrict__ pval,
                                                 const int* __restrict__ pidx,
                                                 int* __restrict__ idxout){
  int r = blockIdx.x*256 + threadIdx.x;
  if (r >= B_*N_) return;
  const float* va = pval + (size_t)r*2*KNN_K;
  const float* vb = va + KNN_K;
  const int*   ia = pidx + (size_t)r*2*KNN_K;
  const int*   ib = ia + KNN_K;
  int i=0, j=0;
  #pragma unroll
  for (int t=0;t<KNN_K;++t){
    float a = va[i], bq = vb[j];
    bool ta = (a >= bq);   // tie -> half 0 (lower ids)
    idxout[(size_t)r*KNN_K + t] = ta ? ia[i] : ib[j];
    i += ta ? 1 : 0; j += ta ? 0 : 1;
  }
}

// ---------------- P/Q GEMM via fp16 2-plane MFMA: Out[M,O] = f * Wsrc[O x Cin]^T ----------------
template<int CP>
__global__ __launch_bounds__(256) void gemm_pq(const short* __restrict__ fbf, size_t plane,
                                               const float* __restrict__ Wsrc, int wstride, int Cin,
                                               float* __restrict__ Out, int O){
  constexpr int BK = (CP < 64) ? CP : 64;
  constexpr int SP = BK + 8;
  __shared__ short Ah[128*SP];
  __shared__ short Am[128*SP];
  __shared__ short Wh[64*SP];
  __shared__ short Wm[64*SP];
  int obl = O >> 6;
  int bo = ((int)blockIdx.x % obl) << 6;
  int bm = ((int)blockIdx.x / obl) << 7;
  int tid = threadIdx.x;
  int w = tid >> 6, lane = tid & 63;
  int fr = lane & 15, hi = lane >> 4;
  f32x4 accH[2][4], accM[2][4];
  #pragma unroll
  for (int g=0; g<2; ++g)
    #pragma unroll
    for (int ct=0; ct<4; ++ct){ accH[g][ct] = (f32x4){0.f,0.f,0.f,0.f}; accM[g][ct] = accH[g][ct]; }

  for (int k0=0; k0<CP; k0+=BK){
    __syncthreads();
    for (int i=tid; i < 128*(BK/8); i += 256){
      int r = i/(BK/8), cq = i%(BK/8);
      size_t src = ((size_t)bm + r)*CP + k0 + cq*8;
      *(f16x8*)&Ah[r*SP + cq*8] = *(const f16x8*)&fbf[src];
      *(f16x8*)&Am[r*SP + cq*8] = *(const f16x8*)&fbf[plane + src];
    }
    for (int i=tid; i < 64*(BK/8); i += 256){
      int r = i/(BK/8), cq = i%(BK/8);
      f16x8 vh, vm;
      #pragma unroll
      for (int e=0;e<8;++e){
        int c = k0 + cq*8 + e;
        float v = (c < Cin) ? Wsrc[(size_t)(bo + r)*wstride + c] : 0.f;
        _Float16 h = (_Float16)v;
        vh[e] = h;
        vm[e] = (_Float16)((v - (float)h) * 2048.f);
      }
      *(f16x8*)&Wh[r*SP + cq*8] = vh;
      *(f16x8*)&Wm[r*SP + cq*8] = vm;
    }
    __syncthreads();
    #pragma unroll
    for (int kc=0; kc<BK/32; ++kc){
      f16x8 a0h = *(const f16x8*)&Ah[(w*32 +      fr)*SP + kc*32 + hi*8];
      f16x8 a0m = *(const f16x8*)&Am[(w*32 +      fr)*SP + kc*32 + hi*8];
      f16x8 a1h = *(const f16x8*)&Ah[(w*32 + 16 + fr)*SP + kc*32 + hi*8];
      f16x8 a1m = *(const f16x8*)&Am[(w*32 + 16 + fr)*SP + kc*32 + hi*8];
      #pragma unroll
      for (int ct=0; ct<4; ++ct){
        f16x8 bh = *(const f16x8*)&Wh[(ct*16 + fr)*SP + kc*32 + hi*8];
        f16x8 bm = *(const f16x8*)&Wm[(ct*16 + fr)*SP + kc*32 + hi*8];
        accH[0][ct] = __builtin_amdgcn_mfma_f32_16x16x32_f16(a0h, bh, accH[0][ct], 0,0,0);
        accM[0][ct] = __builtin_amdgcn_mfma_f32_16x16x32_f16(a0m, bh, accM[0][ct], 0,0,0);
        accM[0][ct] = __builtin_amdgcn_mfma_f32_16x16x32_f16(a0h, bm, accM[0][ct], 0,0,0);
        accH[1][ct] = __builtin_amdgcn_mfma_f32_16x16x32_f16(a1h, bh, accH[1][ct], 0,0,0);
        accM[1][ct] = __builtin_amdgcn_mfma_f32_16x16x32_f16(a1m, bh, accM[1][ct], 0,0,0);
        accM[1][ct] = __builtin_amdgcn_mfma_f32_16x16x32_f16(a1h, bm, accM[1][ct], 0,0,0);
      }
    }
  }
  #pragma unroll
  for (int g=0; g<2; ++g)
    #pragma unroll
    for (int ct=0; ct<4; ++ct)
      #pragma unroll
      for (int reg=0; reg<4; ++reg){
        int row = bm + w*32 + g*16 + hi*4 + reg;
        Out[(size_t)row*O + bo + ct*16 + fr] = accH[g][ct][reg] + IMS*accM[g][ct][reg];
      }
}

// ---------------- conv5 MFMA GEMM: C[M,512] = A[M,512]fp32 x W[512,512]fp32^T (bf16 staged) ----------------
__global__ __launch_bounds__(256) void gemm_bf16(const float* __restrict__ A,
                                                 const float* __restrict__ Wt,
                                                 float* __restrict__ C){
  __shared__ short As[128*72];
  __shared__ short Bs[64*72];
  int bm = (int)(blockIdx.x >> 3) << 7;
  int bo = (int)(blockIdx.x & 7) << 6;
  int tid = threadIdx.x;
  int w = tid >> 6, lane = tid & 63;
  int fr = lane & 15, hi = lane >> 4;
  f32x4 acc[2][4];
  #pragma unroll
  for (int g=0; g<2; ++g)
    #pragma unroll
    for (int ct=0; ct<4; ++ct) acc[g][ct] = (f32x4){0.f,0.f,0.f,0.f};

  for (int k0=0; k0<512; k0+=64){
    __syncthreads();
    #pragma unroll 2
    for (int i = tid; i < 1024; i += 256){
      int r = i >> 3, cq = i & 7;
      const float* src = &A[(size_t)(bm + r)*512 + k0 + cq*8];
      bf16x8 v;
      #pragma unroll
      for (int e=0;e<8;++e) v[e] = bfbits(src[e]);
      *(bf16x8*)&As[r*72 + cq*8] = v;
    }
    #pragma unroll 2
    for (int i = tid; i < 512; i += 256){
      int r = i >> 3, cq = i & 7;
      const float* src = &Wt[(size_t)(bo + r)*512 + k0 + cq*8];
      bf16x8 v;
      #pragma unroll
      for (int e=0;e<8;++e) v[e] = bfbits(src[e]);
      *(bf16x8*)&Bs[r*72 + cq*8] = v;
    }
    __syncthreads();
    #pragma unroll
    for (int kc=0; kc<2; ++kc){
      bf16x8 a0 = *(const bf16x8*)&As[(w*32 +      fr)*72 + kc*32 + hi*8];
      bf16x8 a1 = *(const bf16x8*)&As[(w*32 + 16 + fr)*72 + kc*32 + hi*8];
      #pragma unroll
      for (int ct=0; ct<4; ++ct){
        bf16x8 bb = *(const bf16x8*)&Bs[(ct*16 + fr)*72 + kc*32 + hi*8];
        acc[0][ct] = __builtin_amdgcn_mfma_f32_16x16x32_bf16(a0, bb, acc[0][ct], 0,0,0);
        acc[1][ct] = __builtin_amdgcn_mfma_f32_16x16x32_bf16(a1, bb, acc[1][ct], 0,0,0);
      }
    }
  }
  #pragma unroll
  for (int g=0; g<2; ++g)
    #pragma unroll
    for (int ct=0; ct<4; ++ct)
      #pragma unroll
      for (int reg=0; reg<4; ++reg){
        int row = bm + w*32 + g*16 + hi*4 + reg;
        C[(size_t)row*512 + bo + ct*16 + fr] = acc[g][ct][reg];
      }
}

// ---------------- wq = wB - wA ----------------
__global__ void wq_kernel(const float* __restrict__ w, float* __restrict__ wq, int Cin, int O){
  int i = blockIdx.x*blockDim.x + threadIdx.x;
  if (i >= O*Cin) return;
  int o = i / Cin, c = i - o*Cin;
  wq[i] = w[(size_t)o*2*Cin + Cin + c] - w[(size_t)o*2*Cin + c];
}

__global__ void zero_f_kernel(float* p, int n){
  int i = blockIdx.x*blockDim.x + threadIdx.x;
  if (i < n) p[i] = 0.f;
}
__global__ void zero_u_kernel(unsigned* p, int n){
  int i = blockIdx.x*blockDim.x + threadIdx.x;
  if (i < n) p[i] = 0u;
}

// ---------------- edge aggregation: gather P, stats + selected extreme ----------------
__global__ __launch_bounds__(256) void edge_agg(const float* __restrict__ P, const float* __restrict__ Q,
      const int* __restrict__ idx, const float* __restrict__ gamma,
      float* __restrict__ S, float* __restrict__ sums, float* __restrict__ sumsq, int O){
  const int ROWS = 64;
  int rpi = 256 / O;
  int iters = ROWS / rpi;
  int row0 = blockIdx.x * ROWS;
  int tid = threadIdx.x;
  int o  = tid % O;
  int rl = tid / O;
  int b  = row0 / N_;
  __shared__ int sidx[4][KNN_K];
  __shared__ float s1[256], s2[256];
  float g = gamma[o];
  float csum=0.f, csumsq=0.f;
  for (int it=0; it<iters; ++it){
    __syncthreads();
    if (tid < KNN_K*rpi) sidx[tid/KNN_K][tid%KNN_K] = idx[(size_t)(row0 + it*rpi)*KNN_K + tid];
    __syncthreads();
    int row = row0 + it*rpi + rl;
    float q = Q[(size_t)row*O + o];
    float mx=-1e30f, mn=1e30f, s=0.f, ss=0.f;
    #pragma unroll
    for (int k=0;k<KNN_K;++k){
      int m = sidx[rl][k];
      float p = P[((size_t)b*N_ + m)*O + o];
      mx = fmaxf(mx,p); mn = fminf(mn,p);
      float y = p + q; s += y; ss += y*y;
    }
    csum += s; csumsq += ss;
    S[(size_t)row*O + o] = (g >= 0.f ? mx : mn) + q;
  }
  s1[tid]=0.f; s2[tid]=0.f;
  __syncthreads();
  atomicAdd(&s1[o], csum); atomicAdd(&s2[o], csumsq);
  __syncthreads();
  if (tid < O){ atomicAdd(&sums[tid], s1[tid]); atomicAdd(&sumsq[tid], s2[tid]); }
}

// ---------------- BN finalize ----------------
__global__ void bn_finalize(const float* __restrict__ sums, const float* __restrict__ sumsq,
                            const float* __restrict__ gamma, const float* __restrict__ beta,
                            float invM, float* __restrict__ scale, float* __restrict__ shift, int O){
  int o = blockIdx.x*blockDim.x + threadIdx.x;
  if (o >= O) return;
  float mu = sums[o]*invM;
  float var = sumsq[o]*invM - mu*mu;
  float rs = rsqrtf(var + EPS_);
  float sc = gamma[o]*rs;
  scale[o] = sc; shift[o] = beta[o] - mu*sc;
}

// ---------------- apply affine+lrelu, write into cat ----------------
__global__ void apply_write(const float* __restrict__ S, const float* __restrict__ scale,
                            const float* __restrict__ shift, float* __restrict__ cat, int off, int O){
  int i = blockIdx.x*blockDim.x + threadIdx.x;
  if (i >= B_*N_*O) return;
  int row = i / O, o = i - row*O;
  float v = S[i]*scale[o] + shift[o];
  cat[(size_t)row*512 + off + o] = lrelu(v);
}

// ---------------- conv5 stats ----------------
__global__ __launch_bounds__(256) void conv5_stats(const float* __restrict__ Y, const float* __restrict__ g5,
      float* __restrict__ sums, float* __restrict__ sumsq, unsigned* __restrict__ maxenc){
  int bb = blockIdx.x / 16;
  int n0 = (blockIdx.x % 16) * 128;
  int tid = threadIdx.x;
  float s0=0.f, s1=0.f, q0=0.f, q1=0.f, m0=-1e30f, m1=-1e30f;
  float ga = g5[tid], gb = g5[tid+256];
  for (int n=0;n<128;++n){
    size_t base = ((size_t)bb*N_ + n0 + n)*512;
    float ya = Y[base + tid];
    float yb = Y[base + tid + 256];
    s0 += ya; q0 += ya*ya;
    s1 += yb; q1 += yb*yb;
    m0 = fmaxf(m0, ga>=0.f ? ya : -ya);
    m1 = fmaxf(m1, gb>=0.f ? yb : -yb);
  }
  atomicAdd(&sums[tid],      s0); atomicAdd(&sumsq[tid],      q0);
  atomicAdd(&sums[tid+256],  s1); atomicAdd(&sumsq[tid+256],  q1);
  atomicMax(&maxenc[bb*512 + tid],       encf(m0));
  atomicMax(&maxenc[bb*512 + tid + 256], encf(m1));
}

// ---------------- pool ----------------
__global__ void pool_kernel(const unsigned* __restrict__ maxenc, const float* __restrict__ scale,
                            const float* __restrict__ shift, const float* __restrict__ g5,
                            float* __restrict__ pooled){
  int i = blockIdx.x*blockDim.x + threadIdx.x;
  if (i >= B_*512) return;
  int o = i & 511;
  float t = decf(maxenc[i]);
  float y = g5[o] >= 0.f ? t : -t;
  pooled[i] = lrelu(y*scale[o] + shift[o]);
}

// ---------------- final projection ----------------
__global__ void final_mm(const float* __restrict__ pooled, const float* __restrict__ we,
                         float* __restrict__ out){
  int i = blockIdx.x*blockDim.x + threadIdx.x;
  if (i >= B_*128) return;
  int b = i >> 7, j = i & 127;
  const float4* pp = (const float4*)(pooled + (size_t)b*512);
  const float4* wp = (const float4*)(we + (size_t)j*512);
  float s = 0.f;
  for (int c=0;c<128;++c){
    float4 a = pp[c], w = wp[c];
    s += a.x*w.x + a.y*w.y + a.z*w.z + a.w*w.w;
  }
  out[i] = s;
}

// ---------------- driver ----------------
struct Ws {
  float* cat; float* P; float* Q; float* S; int* idx; float* xx;
  float* sums; float* sumsq; float* scale; float* shift;
  float* wq; unsigned* maxenc; float* pooled; short* fbf;
  float* pval; int* pidx;
};

template<int C, int CP>
static void run_layer(const Ws& W, const float* f, int lda, int O,
                      const float* w, const float* g, const float* bt,
                      int off_out, hipStream_t stream){
  const int M = B_*N_;
  size_t plane = (size_t)M*CP;
  convert_kernel<C, CP><<<M/4, 256, 0, stream>>>(f, lda, W.fbf, plane, W.xx);
  knn_nb<CP><<<B_*(N_/16)*2, 64, 0, stream>>>(W.fbf, plane, W.xx, W.pval, W.pidx);
  knn_merge<<<(M+255)/256, 256, 0, stream>>>(W.pval, W.pidx, W.idx);
  int nwq = O*C;
  wq_kernel<<<(nwq+255)/256, 256, 0, stream>>>(w, W.wq, C, O);
  int grid = (M/128)*(O/64);
  gemm_pq<CP><<<grid, 256, 0, stream>>>(W.fbf, plane, w,    2*C, C, W.P, O);
  gemm_pq<CP><<<grid, 256, 0, stream>>>(W.fbf, plane, W.wq, C,   C, W.Q, O);
  zero_f_kernel<<<4, 256, 0, stream>>>(W.sums, 1024);
  edge_agg<<<M/64, 256, 0, stream>>>(W.P, W.Q, W.idx, g, W.S, W.sums, W.sumsq, O);
  bn_finalize<<<(O+255)/256, 256, 0, stream>>>(W.sums, W.sumsq, g, bt,
                                               1.f/((float)M*KNN_K), W.scale, W.shift, O);
  apply_write<<<(M*O+255)/256, 256, 0, stream>>>(W.S, W.scale, W.shift, W.cat, off_out, O);
}

extern "C" void kernel_launch(void* const* d_in, const int* in_sizes, int n_in,
                              void* d_out, int out_size, void* d_ws, size_t ws_size,
                              hipStream_t stream) {
  const float* x  = (const float*)d_in[0];
  const float* w1 = (const float*)d_in[1];
  const float* g1 = (const float*)d_in[2];
  const float* b1 = (const float*)d_in[3];
  const float* w2 = (const float*)d_in[4];
  const float* g2 = (const float*)d_in[5];
  const float* b2 = (const float*)d_in[6];
  const float* w3 = (const float*)d_in[7];
  const float* g3 = (const float*)d_in[8];
  const float* b3 = (const float*)d_in[9];
  const float* w4 = (const float*)d_in[10];
  const float* g4 = (const float*)d_in[11];
  const float* b4 = (const float*)d_in[12];
  const float* w5 = (const float*)d_in[13];
  const float* g5 = (const float*)d_in[14];
  const float* b5 = (const float*)d_in[15];
  const float* we = (const float*)d_in[16];

  char* ws = (char*)d_ws;
  Ws W;
  size_t off = 0;
  W.cat   = (float*)(ws + off); off += (size_t)16*2048*512*4;
  W.P     = (float*)(ws + off); off += (size_t)16*2048*256*4;
  W.Q     = (float*)(ws + off); off += (size_t)16*2048*256*4;
  W.S     = (float*)(ws + off); off += (size_t)16*2048*256*4;
  W.idx   = (int*)  (ws + off); off += (size_t)16*2048*20*4;
  W.xx    = (float*)(ws + off); off += (size_t)16*2048*4;
  W.sums  = (float*)(ws + off); off += 512*4;
  W.sumsq = (float*)(ws + off); off += 512*4;
  W.scale = (float*)(ws + off); off += 512*4;
  W.shift = (float*)(ws + off); off += 512*4;
  W.wq    = (float*)(ws + off); off += (size_t)256*128*4;
  W.maxenc= (unsigned*)(ws + off); off += (size_t)16*512*4;
  W.pooled= (float*)(ws + off); off += (size_t)16*512*4;
  W.fbf   = (short*)W.S;            // fbf live [convert, gemm_pq]; S live [edge_agg, apply_write]
  W.pval  = W.Q;                    // partials live [knn, merge]; Q live [gemm_pq, edge_agg]
  W.pidx  = (int*)(W.Q + (size_t)2*16*2048*KNN_K);

  const int M = B_*N_;

  run_layer<3,   32>(W, x,           3,   64,  w1, g1, b1, 0,   stream);
  run_layer<64,  64>(W, W.cat,       512, 64,  w2, g2, b2, 64,  stream);
  run_layer<64,  64>(W, W.cat + 64,  512, 128, w3, g3, b3, 128, stream);
  run_layer<128,128>(W, W.cat + 128, 512, 256, w4, g4, b4, 256, stream);

  // conv5 via bf16 MFMA; y5 reuses P+Q region
  float* y5 = W.P;
  gemm_bf16<<<(M/128)*8, 256, 0, stream>>>(W.cat, w5, y5);
  zero_f_kernel<<<4, 256, 0, stream>>>(W.sums, 1024);
  zero_u_kernel<<<32, 256, 0, stream>>>(W.maxenc, 16*512);
  conv5_stats<<<B_*16, 256, 0, stream>>>(y5, g5, W.sums, W.sumsq, W.maxenc);
  bn_finalize<<<2, 256, 0, stream>>>(W.sums, W.sumsq, g5, b5, 1.f/(float)M, W.scale, W.shift, 512);
  pool_kernel<<<(16*512+255)/256, 256, 0, stream>>>(W.maxenc, W.scale, W.shift, g5, W.pooled);
  final_mm<<<(16*128+255)/256, 256, 0, stream>>>(W.pooled, we, (float*)d_out);
}

// Round 12
// 1162.176 us; speedup vs baseline: 1.6009x; 1.1220x over previous
//
#include <hip/hip_runtime.h>
#include <hip/hip_bf16.h>
#include <cstdint>

#define B_ 16
#define N_ 2048
#define KNN_K 20
#define EPS_ 1e-5f
#define SLOPE_ 0.2f
#define IMS 4.8828125e-4f   // 1/2048

typedef __attribute__((ext_vector_type(4))) float f32x4;
typedef __attribute__((ext_vector_type(8))) short bf16x8;
typedef __attribute__((ext_vector_type(8))) _Float16 f16x8;

static __device__ __forceinline__ float lrelu(float v){ return v > 0.f ? v : SLOPE_*v; }

static __device__ __forceinline__ unsigned encf(float f){
  unsigned b = __float_as_uint(f);
  return (b & 0x80000000u) ? ~b : (b | 0x80000000u);
}
static __device__ __forceinline__ float decf(unsigned u){
  unsigned b = (u & 0x80000000u) ? (u ^ 0x80000000u) : ~u;
  return __uint_as_float(b);
}
static __device__ __forceinline__ short bfbits(float v){
  __hip_bfloat16 h = __float2bfloat16(v);
  return *reinterpret_cast<short*>(&h);
}
static __device__ __forceinline__ short h16(float v){
  _Float16 h = (_Float16)v;
  return *reinterpret_cast<short*>(&h);
}
static __device__ __forceinline__ float h2f(short s){
  _Float16 h = *reinterpret_cast<_Float16*>(&s);
  return (float)h;
}

// ---------------- convert: f -> 2 fp16 planes (h, (v-h)*2048) + xx (fp32) ----------------
template<int C, int CP>
__global__ __launch_bounds__(256) void convert_kernel(const float* __restrict__ f, int lda,
                                                      short* __restrict__ fbf, size_t plane,
                                                      float* __restrict__ xx){
  int wid  = (blockIdx.x * 256 + threadIdx.x) >> 6;   // one wave per row
  int lane = threadIdx.x & 63;
  if (wid >= B_*N_) return;
  const float* p = f + (size_t)wid*lda;
  float s = 0.f;
  for (int c = lane; c < CP; c += 64){
    float v = (c < C) ? p[c] : 0.f;
    short h = h16(v);
    short m = h16((v - h2f(h)) * 2048.f);
    size_t o = (size_t)wid*CP + c;
    fbf[o] = h;
    fbf[plane + o] = m;
    s += v*v;
  }
  #pragma unroll
  for (int off=32; off; off>>=1) s += __shfl_down(s, off);
  if (lane==0) xx[wid] = s;
}

// ---------------- fused MFMA distance (fp16 2-plane) + wave-coop top-20, m-split (r8-proven) ----------------
template<int CP>
__global__ __launch_bounds__(256, 2) void knn_mfma(const short* __restrict__ fbf, size_t plane,
                                                const float* __restrict__ xx,
                                                float* __restrict__ pval, int* __restrict__ pidx){
  constexpr int SP = CP + 8;          // shorts per LDS row
  constexpr int CH = CP/8;
  constexpr int KC = CP/32;
  constexpr int PFH = CP/32;          // 16B chunks per thread, H plane only
  constexpr int FMBS = 2*64*SP;       // fmb shorts
  constexpr bool ALIAS = (FMBS*2 >= 64*65*4);
  constexpr unsigned LDSB = ALIAS ? (unsigned)(FMBS*2) : (unsigned)(FMBS*2 + 64*65*4);
  __shared__ __align__(16) char ldsbuf[LDSB];
  short* fmb = (short*)ldsbuf;
  float* dtile = ALIAS ? (float*)ldsbuf : (float*)(ldsbuf + FMBS*2);
  __shared__ float xn_s[64], xm_s[64];

  int b   = blockIdx.x >> 6;
  int rem = blockIdx.x & 63;
  int n0  = (rem >> 1) << 6;
  int mh  = rem & 1;
  int mbase = mh << 10;
  int tid = threadIdx.x;
  int w    = tid >> 6;
  int lane = tid & 63;
  int fr = lane & 15, hi = lane >> 4;
  int r_loc = lane >> 2, csub = lane & 3;
  int gb = lane & 60;
  int myrow = w*16 + r_loc;
  size_t browoff = (size_t)b * N_;

  // fn A-fragments -- m-tile invariant, registers
  f16x8 aH[KC], aM[KC];
  {
    size_t arow = (browoff + n0 + w*16 + fr) * (size_t)CP;
    #pragma unroll
    for (int kc=0; kc<KC; ++kc){
      aH[kc] = *(const f16x8*)&fbf[arow + kc*32 + hi*8];
      aM[kc] = *(const f16x8*)&fbf[plane + arow + kc*32 + hi*8];
    }
  }
  if (tid < 64) xn_s[tid] = xx[browoff + n0 + tid];

  float sv[5]; int si[5];
  #pragma unroll
  for (int j=0;j<5;++j){ sv[j] = -1e30f; si[j] = 0x7FFFFFFF; }

  f16x8 pf[PFH];          // H-plane prefetch only
  float xmreg = 0.f;
  auto PFLOAD = [&](int mt){
    int m0 = mbase + (mt<<6);
    #pragma unroll
    for (int j=0;j<PFH;++j){
      int i = tid + j*256;
      int r = i/CH, cq = i - r*CH;
      pf[j] = *(const f16x8*)&fbf[(browoff + m0 + r)*(size_t)CP + cq*8];
    }
    if (tid < 64) xmreg = xx[browoff + m0 + tid];
  };
  auto WRITEPF = [&](int mt){
    int m0 = mbase + (mt<<6);
    #pragma unroll
    for (int j=0;j<PFH;++j){
      int i = tid + j*256;
      int r = i/CH, cq = i - r*CH;
      *(f16x8*)&fmb[r*SP + cq*8] = pf[j];
    }
    #pragma unroll
    for (int j=0;j<PFH;++j){   // M plane: stream global -> LDS
      int i = tid + j*256;
      int r = i/CH, cq = i - r*CH;
      f16x8 v = *(const f16x8*)&fbf[plane + (browoff + m0 + r)*(size_t)CP + cq*8];
      *(f16x8*)&fmb[64*SP + r*SP + cq*8] = v;
    }
    if (tid < 64) xm_s[tid] = xmreg;
  };

  PFLOAD(0);
  WRITEPF(0);
  __syncthreads();

  for (int mt = 0; mt < 16; ++mt){
    int m0 = mbase + (mt << 6);
    if (mt + 1 < 16) PFLOAD(mt + 1);

    f32x4 accH[4], accM[4];
    #pragma unroll
    for (int ct=0; ct<4; ++ct){ accH[ct] = (f32x4){0.f,0.f,0.f,0.f}; accM[ct] = accH[ct]; }
    const short* BH = fmb;
    const short* BM = fmb + 64*SP;
    #pragma unroll
    for (int kc = 0; kc < KC; ++kc){
      #pragma unroll
      for (int ct=0; ct<4; ++ct){
        int boff = (ct*16 + fr)*SP + kc*32 + hi*8;
        f16x8 bh = *(const f16x8*)&BH[boff];
        f16x8 bm = *(const f16x8*)&BM[boff];
        accH[ct] = __builtin_amdgcn_mfma_f32_16x16x32_f16(aH[kc], bh, accH[ct], 0,0,0);
        accM[ct] = __builtin_amdgcn_mfma_f32_16x16x32_f16(aM[kc], bh, accM[ct], 0,0,0);
        accM[ct] = __builtin_amdgcn_mfma_f32_16x16x32_f16(aH[kc], bm, accM[ct], 0,0,0);
      }
    }
    __syncthreads();   // all fmb reads done (dtile may alias fmb)

    #pragma unroll
    for (int reg=0; reg<4; ++reg){
      int nl = w*16 + hi*4 + reg;
      float xn = xn_s[nl];
      #pragma unroll
      for (int ct=0; ct<4; ++ct)
        dtile[nl*65 + ct*16 + fr] = 2.f*(accH[ct][reg] + IMS*accM[ct][reg]) - xn - xm_s[ct*16 + fr];
    }

    // wave-cooperative selection
    int base = myrow*65 + csub*16;
    float thr = __shfl(sv[4], lane | 3);
    unsigned qm = 0u;
    #pragma unroll
    for (int jj=0; jj<16; ++jj){
      float v = dtile[base + jj];
      qm |= (v > thr) ? (1u << jj) : 0u;
    }
    unsigned long long bal = __ballot(qm != 0u);
    while (bal){
      unsigned nib = (unsigned)((bal >> gb) & 0xFull);
      int leader = nib ? (gb + (int)__builtin_ctz(nib)) : 64;
      int bbit = (int)__builtin_ctz(qm | 0x10000u);
      float mv = dtile[base + (bbit & 15)];
      int mid = m0 + (csub << 4) + bbit;
      float cv = __shfl(mv, leader);
      int   cid = __shfl(mid, leader);
      qm = (lane == leader) ? (qm & (qm - 1u)) : qm;
      int cnt = 0;
      #pragma unroll
      for (int j=0;j<5;++j) cnt += (sv[j] >= cv) ? 1 : 0;
      cnt += __shfl_xor(cnt, 1);
      cnt += __shfl_xor(cnt, 2);
      int pos = nib ? cnt : 20;
      float pv = __shfl_up(sv[4], 1);
      int   pi = __shfl_up(si[4], 1);
      #pragma unroll
      for (int j=0;j<5;++j){
        int g = csub*5 + j;
        float ns = (g < pos) ? sv[j] : ((g == pos) ? cv : pv);
        int   ni = (g < pos) ? si[j] : ((g == pos) ? cid : pi);
        pv = sv[j]; pi = si[j];
        sv[j] = ns; si[j] = ni;
      }
      bal = __ballot(qm != 0u);
    }

    if (mt + 1 < 16){
      if constexpr (ALIAS){
        __syncthreads();
        WRITEPF(mt + 1);
        __syncthreads();
      } else {
        WRITEPF(mt + 1);
        __syncthreads();
      }
    }
  }

  size_t orow = browoff + n0 + myrow;
  float* pvo = pval + (orow*2 + mh)*KNN_K + csub*5;
  int*   pio = pidx + (orow*2 + mh)*KNN_K + csub*5;
  #pragma unroll
  for (int j=0;j<5;++j){ pvo[j] = sv[j]; pio[j] = si[j]; }
}

// ---------------- merge two sorted-20 partial lists per row ----------------
__global__ __launch_bounds__(256) void knn_merge(const float* __restrict__ pval,
                                                 const int* __restrict__ pidx,
                                                 int* __restrict__ idxout){
  int r = blockIdx.x*256 + threadIdx.x;
  if (r >= B_*N_) return;
  const float* va = pval + (size_t)r*2*KNN_K;
  const float* vb = va + KNN_K;
  const int*   ia = pidx + (size_t)r*2*KNN_K;
  const int*   ib = ia + KNN_K;
  int i=0, j=0;
  #pragma unroll
  for (int t=0;t<KNN_K;++t){
    float a = va[i], bq = vb[j];
    bool ta = (a >= bq);   // tie -> half 0 (lower ids)
    idxout[(size_t)r*KNN_K + t] = ta ? ia[i] : ib[j];
    i += ta ? 1 : 0; j += ta ? 0 : 1;
  }
}

// ---------------- combined P+Q GEMM (fp16 2-plane): A staged once, wq = wB - wA inline ----------------
// 64-row tile, 4 waves x 16 rows. Out P[row,o] = f.wA^T ; Q[row,o] = f.(wB-wA)^T.
template<int CP>
__global__ __launch_bounds__(256) void gemm_pq2(const short* __restrict__ fbf, size_t plane,
                                                const float* __restrict__ Wsrc, int Cin,
                                                float* __restrict__ P, float* __restrict__ Qo, int O){
  constexpr int BK = (CP < 64) ? CP : 64;
  constexpr int SP = BK + 8;
  __shared__ short Ah[64*SP];
  __shared__ short Am[64*SP];
  __shared__ short WAh[64*SP];
  __shared__ short WAm[64*SP];
  __shared__ short WQh[64*SP];
  __shared__ short WQm[64*SP];
  int obl = O >> 6;
  int bo = ((int)blockIdx.x % obl) << 6;
  int bm = ((int)blockIdx.x / obl) << 6;
  int tid = threadIdx.x;
  int w = tid >> 6, lane = tid & 63;
  int fr = lane & 15, hi = lane >> 4;
  f32x4 aPH[4], aPM[4], aQH[4], aQM[4];
  #pragma unroll
  for (int ct=0; ct<4; ++ct){
    aPH[ct] = (f32x4){0.f,0.f,0.f,0.f};
    aPM[ct] = aPH[ct]; aQH[ct] = aPH[ct]; aQM[ct] = aPH[ct];
  }

  for (int k0=0; k0<CP; k0+=BK){
    __syncthreads();
    for (int i=tid; i < 64*(BK/8); i += 256){
      int r = i/(BK/8), cq = i%(BK/8);
      size_t src = ((size_t)bm + r)*CP + k0 + cq*8;
      *(f16x8*)&Ah[r*SP + cq*8] = *(const f16x8*)&fbf[src];
      *(f16x8*)&Am[r*SP + cq*8] = *(const f16x8*)&fbf[plane + src];
    }
    for (int i=tid; i < 64*(BK/8); i += 256){
      int r = i/(BK/8), cq = i%(BK/8);
      f16x8 vah, vam, vqh, vqm;
      #pragma unroll
      for (int e=0;e<8;++e){
        int c = k0 + cq*8 + e;
        float wa = 0.f, wqv = 0.f;
        if (c < Cin){
          wa  = Wsrc[(size_t)(bo + r)*2*Cin + c];
          wqv = Wsrc[(size_t)(bo + r)*2*Cin + Cin + c] - wa;
        }
        _Float16 ha = (_Float16)wa;
        vah[e] = ha;
        vam[e] = (_Float16)((wa - (float)ha) * 2048.f);
        _Float16 hq = (_Float16)wqv;
        vqh[e] = hq;
        vqm[e] = (_Float16)((wqv - (float)hq) * 2048.f);
      }
      *(f16x8*)&WAh[r*SP + cq*8] = vah;
      *(f16x8*)&WAm[r*SP + cq*8] = vam;
      *(f16x8*)&WQh[r*SP + cq*8] = vqh;
      *(f16x8*)&WQm[r*SP + cq*8] = vqm;
    }
    __syncthreads();
    #pragma unroll
    for (int kc=0; kc<BK/32; ++kc){
      f16x8 ah = *(const f16x8*)&Ah[(w*16 + fr)*SP + kc*32 + hi*8];
      f16x8 am = *(const f16x8*)&Am[(w*16 + fr)*SP + kc*32 + hi*8];
      #pragma unroll
      for (int ct=0; ct<4; ++ct){
        int boff = (ct*16 + fr)*SP + kc*32 + hi*8;
        f16x8 bh = *(const f16x8*)&WAh[boff];
        f16x8 bm = *(const f16x8*)&WAm[boff];
        f16x8 qh = *(const f16x8*)&WQh[boff];
        f16x8 qm = *(const f16x8*)&WQm[boff];
        aPH[ct] = __builtin_amdgcn_mfma_f32_16x16x32_f16(ah, bh, aPH[ct], 0,0,0);
        aPM[ct] = __builtin_amdgcn_mfma_f32_16x16x32_f16(am, bh, aPM[ct], 0,0,0);
        aPM[ct] = __builtin_amdgcn_mfma_f32_16x16x32_f16(ah, bm, aPM[ct], 0,0,0);
        aQH[ct] = __builtin_amdgcn_mfma_f32_16x16x32_f16(ah, qh, aQH[ct], 0,0,0);
        aQM[ct] = __builtin_amdgcn_mfma_f32_16x16x32_f16(am, qh, aQM[ct], 0,0,0);
        aQM[ct] = __builtin_amdgcn_mfma_f32_16x16x32_f16(ah, qm, aQM[ct], 0,0,0);
      }
    }
  }
  #pragma unroll
  for (int ct=0; ct<4; ++ct)
    #pragma unroll
    for (int reg=0; reg<4; ++reg){
      int row = bm + w*16 + hi*4 + reg;
      size_t o = (size_t)row*O + bo + ct*16 + fr;
      P[o]  = aPH[ct][reg] + IMS*aPM[ct][reg];
      Qo[o] = aQH[ct][reg] + IMS*aQM[ct][reg];
    }
}

// ---------------- conv5 GEMM (bf16 staged) with fused BN stats + signed max epilogue ----------------
__global__ __launch_bounds__(256) void gemm_bf16_stats(const float* __restrict__ A,
                                                       const float* __restrict__ Wt,
                                                       const float* __restrict__ g5,
                                                       float* __restrict__ sums,
                                                       float* __restrict__ sumsq,
                                                       unsigned* __restrict__ maxenc){
  __shared__ short As[128*72];
  __shared__ short Bs[64*72];
  __shared__ float s1[64], s2[64];
  int bm = (int)(blockIdx.x >> 3) << 7;
  int bo = (int)(blockIdx.x & 7) << 6;
  int tid = threadIdx.x;
  int w = tid >> 6, lane = tid & 63;
  int fr = lane & 15, hi = lane >> 4;
  f32x4 acc[2][4];
  #pragma unroll
  for (int g=0; g<2; ++g)
    #pragma unroll
    for (int ct=0; ct<4; ++ct) acc[g][ct] = (f32x4){0.f,0.f,0.f,0.f};

  for (int k0=0; k0<512; k0+=64){
    __syncthreads();
    #pragma unroll 2
    for (int i = tid; i < 1024; i += 256){
      int r = i >> 3, cq = i & 7;
      const float* src = &A[(size_t)(bm + r)*512 + k0 + cq*8];
      bf16x8 v;
      #pragma unroll
      for (int e=0;e<8;++e) v[e] = bfbits(src[e]);
      *(bf16x8*)&As[r*72 + cq*8] = v;
    }
    #pragma unroll 2
    for (int i = tid; i < 512; i += 256){
      int r = i >> 3, cq = i & 7;
      const float* src = &Wt[(size_t)(bo + r)*512 + k0 + cq*8];
      bf16x8 v;
      #pragma unroll
      for (int e=0;e<8;++e) v[e] = bfbits(src[e]);
      *(bf16x8*)&Bs[r*72 + cq*8] = v;
    }
    __syncthreads();
    #pragma unroll
    for (int kc=0; kc<2; ++kc){
      bf16x8 a0 = *(const bf16x8*)&As[(w*32 +      fr)*72 + kc*32 + hi*8];
      bf16x8 a1 = *(const bf16x8*)&As[(w*32 + 16 + fr)*72 + kc*32 + hi*8];
      #pragma unroll
      for (int ct=0; ct<4; ++ct){
        bf16x8 bb = *(const bf16x8*)&Bs[(ct*16 + fr)*72 + kc*32 + hi*8];
        acc[0][ct] = __builtin_amdgcn_mfma_f32_16x16x32_bf16(a0, bb, acc[0][ct], 0,0,0);
        acc[1][ct] = __builtin_amdgcn_mfma_f32_16x16x32_bf16(a1, bb, acc[1][ct], 0,0,0);
      }
    }
  }

  // epilogue: per-column stats (sum, sumsq, signed-max) -- no y5 materialization
  __syncthreads();
  if (tid < 64){ s1[tid] = 0.f; s2[tid] = 0.f; }
  __syncthreads();
  int bidx = bm >> 11;   // batch index (2048 % 128 == 0: one batch per block)
  #pragma unroll
  for (int ct=0; ct<4; ++ct){
    int o = bo + ct*16 + fr;
    float ga = g5[o];
    float s = 0.f, ss = 0.f, mx = -1e30f;
    #pragma unroll
    for (int g=0; g<2; ++g)
      #pragma unroll
      for (int reg=0; reg<4; ++reg){
        float v = acc[g][ct][reg];
        s += v; ss += v*v;
        float sel = ga >= 0.f ? v : -v;
        mx = fmaxf(mx, sel);
      }
    s  += __shfl_xor(s, 16);  s  += __shfl_xor(s, 32);
    ss += __shfl_xor(ss, 16); ss += __shfl_xor(ss, 32);
    mx = fmaxf(mx, __shfl_xor(mx, 16)); mx = fmaxf(mx, __shfl_xor(mx, 32));
    if (hi == 0){
      atomicAdd(&s1[ct*16 + fr], s);
      atomicAdd(&s2[ct*16 + fr], ss);
      atomicMax(&maxenc[bidx*512 + o], encf(mx));
    }
  }
  __syncthreads();
  if (tid < 64){
    atomicAdd(&sums[bo + tid],  s1[tid]);
    atomicAdd(&sumsq[bo + tid], s2[tid]);
  }
}

__global__ void zero_f_kernel(float* p, int n){
  int i = blockIdx.x*blockDim.x + threadIdx.x;
  if (i < n) p[i] = 0.f;
}
__global__ void zero_u_kernel(unsigned* p, int n){
  int i = blockIdx.x*blockDim.x + threadIdx.x;
  if (i < n) p[i] = 0u;
}

// ---------------- edge aggregation: gather P, stats + selected extreme ----------------
__global__ __launch_bounds__(256) void edge_agg(const float* __restrict__ P, const float* __restrict__ Q,
      const int* __restrict__ idx, const float* __restrict__ gamma,
      float* __restrict__ S, float* __restrict__ sums, float* __restrict__ sumsq, int O){
  const int ROWS = 64;
  int rpi = 256 / O;
  int iters = ROWS / rpi;
  int row0 = blockIdx.x * ROWS;
  int tid = threadIdx.x;
  int o  = tid % O;
  int rl = tid / O;
  int b  = row0 / N_;
  __shared__ int sidx[4][KNN_K];
  __shared__ float s1[256], s2[256];
  float g = gamma[o];
  float csum=0.f, csumsq=0.f;
  for (int it=0; it<iters; ++it){
    __syncthreads();
    if (tid < KNN_K*rpi) sidx[tid/KNN_K][tid%KNN_K] = idx[(size_t)(row0 + it*rpi)*KNN_K + tid];
    __syncthreads();
    int row = row0 + it*rpi + rl;
    float q = Q[(size_t)row*O + o];
    float mx=-1e30f, mn=1e30f, s=0.f, ss=0.f;
    #pragma unroll
    for (int k=0;k<KNN_K;++k){
      int m = sidx[rl][k];
      float p = P[((size_t)b*N_ + m)*O + o];
      mx = fmaxf(mx,p); mn = fminf(mn,p);
      float y = p + q; s += y; ss += y*y;
    }
    csum += s; csumsq += ss;
    S[(size_t)row*O + o] = (g >= 0.f ? mx : mn) + q;
  }
  s1[tid]=0.f; s2[tid]=0.f;
  __syncthreads();
  atomicAdd(&s1[o], csum); atomicAdd(&s2[o], csumsq);
  __syncthreads();
  if (tid < O){ atomicAdd(&sums[tid], s1[tid]); atomicAdd(&sumsq[tid], s2[tid]); }
}

// ---------------- BN finalize ----------------
__global__ void bn_finalize(const float* __restrict__ sums, const float* __restrict__ sumsq,
                            const float* __restrict__ gamma, const float* __restrict__ beta,
                            float invM, float* __restrict__ scale, float* __restrict__ shift, int O){
  int o = blockIdx.x*blockDim.x + threadIdx.x;
  if (o >= O) return;
  float mu = sums[o]*invM;
  float var = sumsq[o]*invM - mu*mu;
  float rs = rsqrtf(var + EPS_);
  float sc = gamma[o]*rs;
  scale[o] = sc; shift[o] = beta[o] - mu*sc;
}

// ---------------- apply affine+lrelu, write into cat ----------------
__global__ void apply_write(const float* __restrict__ S, const float* __restrict__ scale,
                            const float* __restrict__ shift, float* __restrict__ cat, int off, int O){
  int i = blockIdx.x*blockDim.x + threadIdx.x;
  if (i >= B_*N_*O) return;
  int row = i / O, o = i - row*O;
  float v = S[i]*scale[o] + shift[o];
  cat[(size_t)row*512 + off + o] = lrelu(v);
}

// ---------------- pool ----------------
__global__ void pool_kernel(const unsigned* __restrict__ maxenc, const float* __restrict__ scale,
                            const float* __restrict__ shift, const float* __restrict__ g5,
                            float* __restrict__ pooled){
  int i = blockIdx.x*blockDim.x + threadIdx.x;
  if (i >= B_*512) return;
  int o = i & 511;
  float t = decf(maxenc[i]);
  float y = g5[o] >= 0.f ? t : -t;
  pooled[i] = lrelu(y*scale[o] + shift[o]);
}

// ---------------- final projection ----------------
__global__ void final_mm(const float* __restrict__ pooled, const float* __restrict__ we,
                         float* __restrict__ out){
  int i = blockIdx.x*blockDim.x + threadIdx.x;
  if (i >= B_*128) return;
  int b = i >> 7, j = i & 127;
  const float4* pp = (const float4*)(pooled + (size_t)b*512);
  const float4* wp = (const float4*)(we + (size_t)j*512);
  float s = 0.f;
  for (int c=0;c<128;++c){
    float4 a = pp[c], w = wp[c];
    s += a.x*w.x + a.y*w.y + a.z*w.z + a.w*w.w;
  }
  out[i] = s;
}

// ---------------- driver ----------------
struct Ws {
  float* cat; float* P; float* Q; float* S; int* idx; float* xx;
  float* sums; float* sumsq; float* scale; float* shift;
  unsigned* maxenc; float* pooled; short* fbf;
  float* pval; int* pidx;
};

template<int C, int CP>
static void run_layer(const Ws& W, const float* f, int lda, int O,
                      const float* w, const float* g, const float* bt,
                      int off_out, hipStream_t stream){
  const int M = B_*N_;
  size_t plane = (size_t)M*CP;
  convert_kernel<C, CP><<<M/4, 256, 0, stream>>>(f, lda, W.fbf, plane, W.xx);
  knn_mfma<CP><<<B_*(N_/64)*2, 256, 0, stream>>>(W.fbf, plane, W.xx, W.pval, W.pidx);
  knn_merge<<<(M+255)/256, 256, 0, stream>>>(W.pval, W.pidx, W.idx);
  int grid = (M/64)*(O/64);
  gemm_pq2<CP><<<grid, 256, 0, stream>>>(W.fbf, plane, w, C, W.P, W.Q, O);
  zero_f_kernel<<<4, 256, 0, stream>>>(W.sums, 1024);
  edge_agg<<<M/64, 256, 0, stream>>>(W.P, W.Q, W.idx, g, W.S, W.sums, W.sumsq, O);
  bn_finalize<<<(O+255)/256, 256, 0, stream>>>(W.sums, W.sumsq, g, bt,
                                               1.f/((float)M*KNN_K), W.scale, W.shift, O);
  apply_write<<<(M*O+255)/256, 256, 0, stream>>>(W.S, W.scale, W.shift, W.cat, off_out, O);
}

extern "C" void kernel_launch(void* const* d_in, const int* in_sizes, int n_in,
                              void* d_out, int out_size, void* d_ws, size_t ws_size,
                              hipStream_t stream) {
  const float* x  = (const float*)d_in[0];
  const float* w1 = (const float*)d_in[1];
  const float* g1 = (const float*)d_in[2];
  const float* b1 = (const float*)d_in[3];
  const float* w2 = (const float*)d_in[4];
  const float* g2 = (const float*)d_in[5];
  const float* b2 = (const float*)d_in[6];
  const float* w3 = (const float*)d_in[7];
  const float* g3 = (const float*)d_in[8];
  const float* b3 = (const float*)d_in[9];
  const float* w4 = (const float*)d_in[10];
  const float* g4 = (const float*)d_in[11];
  const float* b4 = (const float*)d_in[12];
  const float* w5 = (const float*)d_in[13];
  const float* g5 = (const float*)d_in[14];
  const float* b5 = (const float*)d_in[15];
  const float* we = (const float*)d_in[16];

  char* ws = (char*)d_ws;
  Ws W;
  size_t off = 0;
  W.cat   = (float*)(ws + off); off += (size_t)16*2048*512*4;
  W.P     = (float*)(ws + off); off += (size_t)16*2048*256*4;
  W.Q     = (float*)(ws + off); off += (size_t)16*2048*256*4;
  W.S     = (float*)(ws + off); off += (size_t)16*2048*256*4;
  W.idx   = (int*)  (ws + off); off += (size_t)16*2048*20*4;
  W.xx    = (float*)(ws + off); off += (size_t)16*2048*4;
  W.sums  = (float*)(ws + off); off += 512*4;
  W.sumsq = (float*)(ws + off); off += 512*4;
  W.scale = (float*)(ws + off); off += 512*4;
  W.shift = (float*)(ws + off); off += 512*4;
  W.maxenc= (unsigned*)(ws + off); off += (size_t)16*512*4;
  W.pooled= (float*)(ws + off); off += (size_t)16*512*4;
  W.fbf   = (short*)W.S;            // fbf live [convert, gemm_pq2]; S live [edge_agg, apply_write]
  W.pval  = W.Q;                    // partials live [knn, merge]; Q live [gemm_pq2, edge_agg]
  W.pidx  = (int*)(W.Q + (size_t)2*16*2048*KNN_K);

  const int M = B_*N_;

  run_layer<3,   32>(W, x,           3,   64,  w1, g1, b1, 0,   stream);
  run_layer<64,  64>(W, W.cat,       512, 64,  w2, g2, b2, 64,  stream);
  run_layer<64,  64>(W, W.cat + 64,  512, 128, w3, g3, b3, 128, stream);
  run_layer<128,128>(W, W.cat + 128, 512, 256, w4, g4, b4, 256, stream);

  // conv5 with fused BN-stats + signed-max epilogue (no y5 materialization)
  zero_f_kernel<<<4, 256, 0, stream>>>(W.sums, 1024);
  zero_u_kernel<<<32, 256, 0, stream>>>(W.maxenc, 16*512);
  gemm_bf16_stats<<<(M/128)*8, 256, 0, stream>>>(W.cat, w5, g5, W.sums, W.sumsq, W.maxenc);
  bn_finalize<<<2, 256, 0, stream>>>(W.sums, W.sumsq, g5, b5, 1.f/(float)M, W.scale, W.shift, 512);
  pool_kernel<<<(16*512+255)/256, 256, 0, stream>>>(W.maxenc, W.scale, W.shift, g5, W.pooled);
  final_mm<<<(16*128+255)/256, 256, 0, stream>>>(W.pooled, we, (float*)d_out);
}